// Round 3
// baseline (553.740 us; speedup 1.0000x reference)
//
#include <hip/hip_runtime.h>

typedef _Float16 half8 __attribute__((ext_vector_type(8)));
typedef _Float16 half4v __attribute__((ext_vector_type(4)));
typedef float floatx4 __attribute__((ext_vector_type(4)));

#define MFMA16(a,b,c) __builtin_amdgcn_mfma_f32_16x16x32_f16((a),(b),(c),0,0,0)
#define EXP2F(x) __builtin_amdgcn_exp2f(x)

// B=8, Cin=768, H=W=64, N=4096, NT=32768, MID=256, INTER=128, OUT=20

__device__ inline void gl_lds16(const _Float16* g, _Float16* l) {
    __builtin_amdgcn_global_load_lds(
        (const __attribute__((address_space(1))) unsigned int*)g,
        (__attribute__((address_space(3))) unsigned int*)l, 16, 0, 0);
}

// ---------------------------------------------------------------------------
// Weight fp32->fp16 conversion. w_theta pre-scaled by log2(e) so attention
// softmax can use native exp2 (exact fold: scaling done in f32 before round).
// ---------------------------------------------------------------------------
__global__ __launch_bounds__(256) void k_convert(
    const float* __restrict__ w_conv, const float* __restrict__ w_theta,
    const float* __restrict__ w_phi, const float* __restrict__ w_g,
    _Float16* __restrict__ w_conv_h, _Float16* __restrict__ w_theta_h,
    _Float16* __restrict__ w_phi_h, _Float16* __restrict__ w_g_h)
{
    int tid = blockIdx.x * 256 + threadIdx.x;
    int nth = gridDim.x * 256;
    for (int i = tid; i < 256 * 768; i += nth) w_conv_h[i] = (_Float16)w_conv[i];
    for (int i = tid; i < 128 * 256; i += nth) {
        w_theta_h[i] = (_Float16)(w_theta[i] * 1.44269504f);
        w_phi_h[i]   = (_Float16)w_phi[i];
        w_g_h[i]     = (_Float16)w_g[i];
    }
}

// ---------------------------------------------------------------------------
// Fold W->BN->out: Acat[32][384] fp16, c0[32] f32.
// ---------------------------------------------------------------------------
__global__ __launch_bounds__(256) void k_fold(
    const float* __restrict__ w_W, const float* __restrict__ b_W,
    const float* __restrict__ gamma, const float* __restrict__ beta,
    const float* __restrict__ mean, const float* __restrict__ var,
    const float* __restrict__ w_out, const float* __restrict__ b_out,
    _Float16* __restrict__ Acat, float* __restrict__ c0)
{
    int u = blockIdx.x, t = threadIdx.x;
    __shared__ float woi[256];
    __shared__ float wcv[256];
    if (u >= 20) {
        for (int k = t; k < 384; k += 256) Acat[u * 384 + k] = (_Float16)0.f;
        if (t == 0) c0[u] = 0.f;
        return;
    }
    {
        float inv = gamma[t] * rsqrtf(var[t] + 1e-5f);
        float wo = w_out[u * 256 + t];
        woi[t] = wo * inv;
        wcv[t] = wo * (b_W[t] * inv + beta[t] - mean[t] * inv);
    }
    __syncthreads();
    for (int k = t; k < 384; k += 256) {
        float v;
        if (k < 128) {
            v = 0.f;
            for (int o = 0; o < 256; ++o) v += woi[o] * w_W[o * 128 + k];
        } else {
            v = w_out[u * 256 + (k - 128)];
        }
        Acat[u * 384 + k] = (_Float16)v;
    }
    if (t == 0) {
        float s = b_out[u];
        for (int o = 0; o < 256; ++o) s += wcv[o];
        c0[u] = s;
    }
}

// ---------------------------------------------------------------------------
// Transpose + convert: x [b][768][4096] fp32 -> xt [(b*4096+n)][768] fp16
// ---------------------------------------------------------------------------
__global__ __launch_bounds__(256) void k_transpose(
    const float* __restrict__ x1, const float* __restrict__ x2,
    _Float16* __restrict__ x1t, _Float16* __restrict__ x2t)
{
    int z = blockIdx.z >> 3, b = blockIdx.z & 7;
    const float* X = (z ? x2 : x1) + (size_t)b * 768 * 4096;
    _Float16* XT = (z ? x2t : x1t) + (size_t)b * 4096 * 768;
    int n0 = blockIdx.x * 64, c0 = blockIdx.y * 64;
    __shared__ float tile[64][65];
    int t = threadIdx.x;
    {
        int c = t >> 2, ns = (t & 3) * 16;
        const float* src = X + (size_t)(c0 + c) * 4096 + n0 + ns;
#pragma unroll
        for (int e = 0; e < 4; ++e)
            *(float4*)&tile[c][ns + e * 4] = *(const float4*)(src + e * 4);
    }
    __syncthreads();
    {
        int n = t >> 2, cs = (t & 3) * 16;
        _Float16 outv[16];
#pragma unroll
        for (int e = 0; e < 16; ++e) outv[e] = (_Float16)tile[cs + e][n];
        _Float16* dst = XT + (size_t)(n0 + n) * 768 + c0 + cs;
        *(half8*)(dst)     = *(half8*)&outv[0];
        *(half8*)(dst + 8) = *(half8*)&outv[8];
    }
}

// ---------------------------------------------------------------------------
// m97-style NT GEMM with global_load_lds staging. Tile 128x128, BK=64.
// A[m][k], B[n][k] both k-contiguous fp16; C[m][n] fp16 out, f32 acc.
// LDS unpadded [128][64] (lds-DMA requires lane-contiguous dest).
// ---------------------------------------------------------------------------
__global__ __launch_bounds__(256) void k_gemm_lds(
    const _Float16* __restrict__ A, const _Float16* __restrict__ B,
    _Float16* __restrict__ C, int K, int ldc)
{
    int m0 = blockIdx.x * 128, n0 = blockIdx.y * 128;
    __shared__ _Float16 As[128 * 64];
    __shared__ _Float16 Bs[128 * 64];
    int t = threadIdx.x, wave = t >> 6, lane = t & 63;
    int wm = (wave >> 1) * 64, wn = (wave & 1) * 64;
    int fl = lane & 15, fq = lane >> 4;
    int lrow = wave * 8 + (lane >> 3);      // + q*32
    int lkoff = (lane & 7) * 8;

    floatx4 acc[4][4];
#pragma unroll
    for (int i = 0; i < 4; ++i)
#pragma unroll
        for (int j = 0; j < 4; ++j) acc[i][j] = (floatx4){0.f, 0.f, 0.f, 0.f};

    for (int ko = 0; ko < K; ko += 64) {
        __syncthreads();
#pragma unroll
        for (int q = 0; q < 4; ++q) {
            int row = q * 32 + lrow;
            gl_lds16(A + (size_t)(m0 + row) * K + ko + lkoff,
                     As + q * 2048 + wave * 512);
            gl_lds16(B + (size_t)(n0 + row) * K + ko + lkoff,
                     Bs + q * 2048 + wave * 512);
        }
        __syncthreads();
#pragma unroll
        for (int kc = 0; kc < 2; ++kc) {
            half8 af[4], bf[4];
#pragma unroll
            for (int i = 0; i < 4; ++i)
                af[i] = *(const half8*)&As[(wm + 16 * i + fl) * 64 + kc * 32 + 8 * fq];
#pragma unroll
            for (int j = 0; j < 4; ++j)
                bf[j] = *(const half8*)&Bs[(wn + 16 * j + fl) * 64 + kc * 32 + 8 * fq];
#pragma unroll
            for (int i = 0; i < 4; ++i)
#pragma unroll
                for (int j = 0; j < 4; ++j) acc[i][j] = MFMA16(af[i], bf[j], acc[i][j]);
        }
    }
#pragma unroll
    for (int i = 0; i < 4; ++i)
#pragma unroll
        for (int j = 0; j < 4; ++j) {
            int row = m0 + wm + 16 * i + 4 * fq;
            int col = n0 + wn + 16 * j + fl;
#pragma unroll
            for (int r = 0; r < 4; ++r)
                C[(size_t)(row + r) * ldc + col] = (_Float16)acc[i][j][r];
        }
}

// ---------------------------------------------------------------------------
// Old NT GEMM (padded LDS, VGPR staging) — kept for the g projection where the
// output needs the attention permutation. perm: col 32B+16h+4q+e -> 32B+8q+4h+e
// ---------------------------------------------------------------------------
__global__ __launch_bounds__(256) void k_gemm_nt(
    const _Float16* __restrict__ A, const _Float16* __restrict__ B,
    _Float16* __restrict__ C, int K, int ldc, int perm)
{
    int m0 = blockIdx.x * 128, n0 = blockIdx.y * 128;
    __shared__ _Float16 As[128][72];
    __shared__ _Float16 Bs[128][72];
    int t = threadIdx.x, wave = t >> 6, lane = t & 63;
    int wm = (wave >> 1) * 64, wn = (wave & 1) * 64;
    int fl = lane & 15, fq = lane >> 4;
    int sr = t >> 2, sc = (t & 3) * 8;

    floatx4 acc[4][4];
#pragma unroll
    for (int i = 0; i < 4; ++i)
#pragma unroll
        for (int j = 0; j < 4; ++j) acc[i][j] = (floatx4){0.f, 0.f, 0.f, 0.f};

    for (int ko = 0; ko < K; ko += 32) {
        __syncthreads();
        half8 av0 = *(const half8*)(A + (size_t)(m0 + sr) * K + ko + sc);
        half8 av1 = *(const half8*)(A + (size_t)(m0 + sr + 64) * K + ko + sc);
        half8 bv0 = *(const half8*)(B + (size_t)(n0 + sr) * K + ko + sc);
        half8 bv1 = *(const half8*)(B + (size_t)(n0 + sr + 64) * K + ko + sc);
        *(half8*)&As[sr][sc] = av0;
        *(half8*)&As[sr + 64][sc] = av1;
        *(half8*)&Bs[sr][sc] = bv0;
        *(half8*)&Bs[sr + 64][sc] = bv1;
        __syncthreads();
        half8 af[4], bf[4];
#pragma unroll
        for (int i = 0; i < 4; ++i) af[i] = *(const half8*)&As[wm + 16 * i + fl][8 * fq];
#pragma unroll
        for (int j = 0; j < 4; ++j) bf[j] = *(const half8*)&Bs[wn + 16 * j + fl][8 * fq];
#pragma unroll
        for (int i = 0; i < 4; ++i)
#pragma unroll
            for (int j = 0; j < 4; ++j) acc[i][j] = MFMA16(af[i], bf[j], acc[i][j]);
    }
#pragma unroll
    for (int i = 0; i < 4; ++i)
#pragma unroll
        for (int j = 0; j < 4; ++j) {
            int row = m0 + wm + 16 * i + 4 * fq;
            int col = n0 + wn + 16 * j + fl;
            int cs2 = perm ? ((col & ~31) | (((col >> 2) & 3) << 3) |
                              (((col >> 4) & 1) << 2) | (col & 3))
                           : col;
#pragma unroll
            for (int r = 0; r < 4; ++r)
                C[(size_t)(row + r) * ldc + cs2] = (_Float16)acc[i][j][r];
        }
}

// ---------------------------------------------------------------------------
// Flash attention, S^T scheme, log2-domain softmax (theta pre-scaled by log2e).
// Grid 1024: b = bi&7 (XCD affinity), iblk = (bi>>3)&31, jh = bi>>8 -> j-quarter.
// Block: 128 i-rows (4 waves x 32i), 1024 j's in 16 chunks of 64.
// ---------------------------------------------------------------------------
__global__ __launch_bounds__(256, 4) void k_attn3(
    const _Float16* __restrict__ theta_t, const _Float16* __restrict__ phi_t,
    const _Float16* __restrict__ gbuf, float* __restrict__ Opart,
    float* __restrict__ Mp, float* __restrict__ Lp)
{
    int bi = blockIdx.x;
    int b = bi & 7;
    int r = bi >> 3;           // 0..127
    int iblk = r & 31, jh = r >> 5;   // jh 0..3
    int i0g = b * 4096 + iblk * 128;
    int t = threadIdx.x, wave = t >> 6, lane = t & 63;
    int fl = lane & 15, fq = lane >> 4;
    int iw = i0g + wave * 32;

    __shared__ _Float16 Ks[64][132];
    __shared__ _Float16 Gs[128][68];

    // Q resident: B-frag layout, lane: n=fl (i), k=8*fq+e
    half8 qf[2][4];
#pragma unroll
    for (int it = 0; it < 2; ++it)
#pragma unroll
        for (int kc = 0; kc < 4; ++kc)
            qf[it][kc] = *(const half8*)(theta_t +
                (size_t)(iw + 16 * it + fl) * 128 + kc * 32 + 8 * fq);

    floatx4 O[8][2];
#pragma unroll
    for (int ct = 0; ct < 8; ++ct)
#pragma unroll
        for (int it = 0; it < 2; ++it) O[ct][it] = (floatx4){0.f, 0.f, 0.f, 0.f};
    float m[2] = {-1e30f, -1e30f}, l[2] = {0.f, 0.f};

    int jbase = b * 4096 + jh * 1024;
    for (int jc = 0; jc < 16; ++jc) {
        int j0g = jbase + jc * 64;
        __syncthreads();
        {   // stage K chunk [64 j][128 c], pad 132
            int jr = t >> 2, cs = (t & 3) * 32;
            const _Float16* src = phi_t + (size_t)(j0g + jr) * 128 + cs;
#pragma unroll
            for (int e = 0; e < 4; ++e)
                *(half8*)&Ks[jr][cs + 8 * e] = *(const half8*)(src + 8 * e);
        }
        {   // stage G chunk [128 c][64 j] (pre-permuted), pad 68
            int c = t >> 1, js = (t & 1) * 32;
            const _Float16* src = gbuf + (size_t)c * 32768 + j0g + js;
#pragma unroll
            for (int e = 0; e < 4; ++e)
                *(half8*)&Gs[c][js + 8 * e] = *(const half8*)(src + 8 * e);
        }
        __syncthreads();

        // S^T[j][i] = sum_c K[j][c] Q[i][c] (log2 domain)
        floatx4 S[4][2];
#pragma unroll
        for (int jt = 0; jt < 4; ++jt)
#pragma unroll
            for (int it = 0; it < 2; ++it) S[jt][it] = (floatx4){0.f, 0.f, 0.f, 0.f};
#pragma unroll
        for (int kc = 0; kc < 4; ++kc)
#pragma unroll
            for (int jt = 0; jt < 4; ++jt) {
                half8 af = *(const half8*)&Ks[16 * jt + fl][kc * 32 + 8 * fq];
                S[jt][0] = MFMA16(af, qf[0][kc], S[jt][0]);
                S[jt][1] = MFMA16(af, qf[1][kc], S[jt][1]);
            }

        // online softmax (exp2): lane holds 16 j-values for i = fl (per it)
        float mx[2];
#pragma unroll
        for (int it = 0; it < 2; ++it) {
            float v = S[0][it][0];
#pragma unroll
            for (int jt = 0; jt < 4; ++jt)
#pragma unroll
                for (int rr = 0; rr < 4; ++rr) v = fmaxf(v, S[jt][it][rr]);
            v = fmaxf(v, __shfl_xor(v, 16, 64));
            v = fmaxf(v, __shfl_xor(v, 32, 64));
            mx[it] = v;
        }
        float mn0 = fmaxf(m[0], mx[0]), mn1 = fmaxf(m[1], mx[1]);
        bool up = (mn0 > m[0]) || (mn1 > m[1]);
        float a0 = EXP2F(m[0] - mn0), a1 = EXP2F(m[1] - mn1);
        m[0] = mn0; m[1] = mn1;

        half8 pk[2][2];
#pragma unroll
        for (int it = 0; it < 2; ++it) {
            float mn = it ? mn1 : mn0;
            float sum = 0.f;
#pragma unroll
            for (int jt = 0; jt < 4; ++jt)
#pragma unroll
                for (int rr = 0; rr < 4; ++rr) {
                    float pv = EXP2F(S[jt][it][rr] - mn);
                    S[jt][it][rr] = pv;
                    sum += pv;
                }
            sum += __shfl_xor(sum, 16, 64);
            sum += __shfl_xor(sum, 32, 64);
            l[it] = l[it] * (it ? a1 : a0) + sum;
#pragma unroll
            for (int kj = 0; kj < 2; ++kj)
#pragma unroll
                for (int e = 0; e < 8; ++e)
                    pk[it][kj][e] = (_Float16)S[2 * kj + (e >> 2)][it][e & 3];
        }
        // rescale O only when some lane's running max moved (usually not)
        if (__ballot(up) != 0ull) {
#pragma unroll
            for (int ct = 0; ct < 8; ++ct)
#pragma unroll
                for (int rr = 0; rr < 4; ++rr) {
                    O[ct][0][rr] *= a0;
                    O[ct][1][rr] *= a1;
                }
        }
#pragma unroll
        for (int kj = 0; kj < 2; ++kj)
#pragma unroll
            for (int ct = 0; ct < 8; ++ct) {
                half8 gf = *(const half8*)&Gs[16 * ct + fl][kj * 32 + 8 * fq];
                O[ct][0] = MFMA16(gf, pk[0][kj], O[ct][0]);
                O[ct][1] = MFMA16(gf, pk[1][kj], O[ct][1]);
            }
    }

#pragma unroll
    for (int it = 0; it < 2; ++it) {
        size_t ig = (size_t)jh * 32768 + iw + 16 * it + fl;
#pragma unroll
        for (int ct = 0; ct < 8; ++ct)
            *(floatx4*)&Opart[ig * 128 + 16 * ct + 4 * fq] = O[ct][it];
        if (fq == 0) { Mp[ig] = m[it]; Lp[ig] = l[it]; }
    }
}

// ---------------------------------------------------------------------------
// Merge 4 j-quarter partials -> y_t [(b*4096+i)][128] fp16 (log2 domain)
// ---------------------------------------------------------------------------
__global__ __launch_bounds__(256) void k_merge(
    const float* __restrict__ Opart, const float* __restrict__ Mp,
    const float* __restrict__ Lp, _Float16* __restrict__ y_t)
{
    int g = blockIdx.x * 256 + threadIdx.x;
    int i = g >> 5, cb = (g & 31) * 4;
    float mk[4], lk[4];
    float M = -1e30f;
#pragma unroll
    for (int k = 0; k < 4; ++k) {
        mk[k] = Mp[k * 32768 + i];
        lk[k] = Lp[k * 32768 + i];
        M = fmaxf(M, mk[k]);
    }
    float w[4], den = 0.f;
#pragma unroll
    for (int k = 0; k < 4; ++k) {
        w[k] = EXP2F(mk[k] - M);
        den += w[k] * lk[k];
    }
    float inv = 1.f / den;
    float acc[4] = {0.f, 0.f, 0.f, 0.f};
#pragma unroll
    for (int k = 0; k < 4; ++k) {
        float4 o = *(const float4*)&Opart[((size_t)k * 32768 + i) * 128 + cb];
        float wk = w[k] * inv;
        acc[0] += wk * o.x; acc[1] += wk * o.y;
        acc[2] += wk * o.z; acc[3] += wk * o.w;
    }
    half4v y;
#pragma unroll
    for (int e = 0; e < 4; ++e) y[e] = (_Float16)acc[e];
    *(half4v*)&y_t[(size_t)i * 128 + cb] = y;
}

// ---------------------------------------------------------------------------
// Epilogue GEMM: out[u][ng] = sum_k Acat[u][k]*concat(y_t,x1p)[ng][k] + c0[u]
// ---------------------------------------------------------------------------
__global__ __launch_bounds__(256) void k_out(
    const _Float16* __restrict__ y_t, const _Float16* __restrict__ x1p_t,
    const _Float16* __restrict__ Acat, const float* __restrict__ c0,
    float* __restrict__ out)
{
    int n0 = blockIdx.x * 128;
    __shared__ _Float16 As[32][72];
    __shared__ _Float16 Bs[128][72];
    __shared__ float c0s[32];
    int t = threadIdx.x, wave = t >> 6, lane = t & 63;
    int fl = lane & 15, fq = lane >> 4;
    int wn = wave * 32;
    if (t < 32) c0s[t] = c0[t];

    floatx4 acc[2][2];
#pragma unroll
    for (int i = 0; i < 2; ++i)
#pragma unroll
        for (int j = 0; j < 2; ++j) acc[i][j] = (floatx4){0.f, 0.f, 0.f, 0.f};

    for (int ko = 0; ko < 12; ++ko) {
        int kg = ko * 32;
        __syncthreads();
        {
            int n = t >> 1, ks = (t & 1) * 16;
            const _Float16* src = (kg < 128)
                ? y_t + (size_t)(n0 + n) * 128 + kg + ks
                : x1p_t + (size_t)(n0 + n) * 256 + (kg - 128) + ks;
            *(half8*)&Bs[n][ks]     = *(const half8*)src;
            *(half8*)&Bs[n][ks + 8] = *(const half8*)(src + 8);
        }
        if (t < 128) {
            int mm = t >> 2, ks = (t & 3) * 8;
            *(half8*)&As[mm][ks] = *(const half8*)(Acat + mm * 384 + kg + ks);
        }
        __syncthreads();
        half8 af[2], bf[2];
#pragma unroll
        for (int mt = 0; mt < 2; ++mt) af[mt] = *(const half8*)&As[16 * mt + fl][8 * fq];
#pragma unroll
        for (int nt = 0; nt < 2; ++nt) bf[nt] = *(const half8*)&Bs[wn + 16 * nt + fl][8 * fq];
#pragma unroll
        for (int mt = 0; mt < 2; ++mt)
#pragma unroll
            for (int nt = 0; nt < 2; ++nt) acc[mt][nt] = MFMA16(af[mt], bf[nt], acc[mt][nt]);
    }
#pragma unroll
    for (int mt = 0; mt < 2; ++mt)
#pragma unroll
        for (int nt = 0; nt < 2; ++nt)
#pragma unroll
            for (int r = 0; r < 4; ++r) {
                int u = 16 * mt + 4 * fq + r;
                if (u < 20) {
                    int ng = n0 + wn + 16 * nt + fl;
                    int b = ng >> 12, n = ng & 4095;
                    out[((size_t)b * 20 + u) * 4096 + n] = acc[mt][nt][r] + c0s[u];
                }
            }
}

// ---------------------------------------------------------------------------
extern "C" void kernel_launch(void* const* d_in, const int* in_sizes, int n_in,
                              void* d_out, int out_size, void* d_ws, size_t ws_size,
                              hipStream_t stream)
{
    const float* x1     = (const float*)d_in[0];
    const float* x2     = (const float*)d_in[1];
    const float* w_conv = (const float*)d_in[2];
    const float* w_theta= (const float*)d_in[3];
    const float* w_phi  = (const float*)d_in[4];
    const float* w_g    = (const float*)d_in[5];
    const float* w_W    = (const float*)d_in[6];
    const float* b_W    = (const float*)d_in[7];
    const float* gamma  = (const float*)d_in[8];
    const float* beta   = (const float*)d_in[9];
    const float* mean   = (const float*)d_in[10];
    const float* var    = (const float*)d_in[11];
    const float* w_out  = (const float*)d_in[12];
    const float* b_out  = (const float*)d_in[13];
    float* out = (float*)d_out;
    char* ws = (char*)d_ws;

    // workspace layout (bytes)
    _Float16* x1t      = (_Float16*)(ws + 0);          // [32768][768] (phase 1)
    _Float16* x2t      = (_Float16*)(ws + 50331648);   // [32768][768] (phase 1)
    _Float16* x1p      = (_Float16*)(ws + 100663296);  // [32768][256] (alive to end)
    _Float16* x2p      = (_Float16*)(ws + 117440512);  // [32768][256] (dead after g)
    // phase 2 (reuses x1t/x2t region):
    _Float16* theta_t  = (_Float16*)(ws + 0);          // [32768][128]
    _Float16* phi_t    = (_Float16*)(ws + 8388608);    // [32768][128]
    _Float16* gbuf     = (_Float16*)(ws + 16777216);   // [128][32768] permuted
    _Float16* y_t      = (_Float16*)(ws + 25165824);   // [32768][128]
    float*    Opart    = (float*)   (ws + 33554432);   // [4][32768][128] f32 (ends 100663296)
    float*    Mp       = (float*)   (ws + 117440512);  // [4][32768] (over dead x2p)
    float*    Lp       = (float*)   (ws + 117964800);  // [4][32768]
    _Float16* w_conv_h = (_Float16*)(ws + 134217728);  // [256][768]
    _Float16* w_theta_h= (_Float16*)(ws + 134610944);  // [128][256] (log2e-scaled)
    _Float16* w_phi_h  = (_Float16*)(ws + 134676480);  // [128][256]
    _Float16* w_g_h    = (_Float16*)(ws + 134742016);  // [128][256]
    _Float16* Acat     = (_Float16*)(ws + 134807552);  // [32][384]
    float*    c0       = (float*)   (ws + 134832128);  // [32]

    k_convert<<<64, 256, 0, stream>>>(w_conv, w_theta, w_phi, w_g,
                                      w_conv_h, w_theta_h, w_phi_h, w_g_h);
    k_fold<<<32, 256, 0, stream>>>(w_W, b_W, gamma, beta, mean, var,
                                   w_out, b_out, Acat, c0);
    k_transpose<<<dim3(64, 12, 16), 256, 0, stream>>>(x1, x2, x1t, x2t);
    k_gemm_lds<<<dim3(256, 2), 256, 0, stream>>>(x1t, w_conv_h, x1p, 768, 256);
    k_gemm_lds<<<dim3(256, 2), 256, 0, stream>>>(x2t, w_conv_h, x2p, 768, 256);
    k_gemm_lds<<<dim3(256, 1), 256, 0, stream>>>(x1p, w_theta_h, theta_t, 256, 128);
    k_gemm_lds<<<dim3(256, 1), 256, 0, stream>>>(x2p, w_phi_h, phi_t, 256, 128);
    k_gemm_nt<<<dim3(1, 256), 256, 0, stream>>>(w_g_h, x2p, gbuf, 256, 32768, 1);
    k_attn3<<<1024, 256, 0, stream>>>(theta_t, phi_t, gbuf, Opart, Mp, Lp);
    k_merge<<<4096, 256, 0, stream>>>(Opart, Mp, Lp, y_t);
    k_out<<<256, 256, 0, stream>>>(y_t, x1p, Acat, c0, out);
    (void)in_sizes; (void)n_in; (void)out_size; (void)ws_size;
}

// Round 4
// 441.214 us; speedup vs baseline: 1.2550x; 1.2550x over previous
//
#include <hip/hip_runtime.h>

typedef _Float16 half8 __attribute__((ext_vector_type(8)));
typedef _Float16 half4v __attribute__((ext_vector_type(4)));
typedef float floatx4 __attribute__((ext_vector_type(4)));

#define MFMA16(a,b,c) __builtin_amdgcn_mfma_f32_16x16x32_f16((a),(b),(c),0,0,0)
#define EXP2F(x) __builtin_amdgcn_exp2f(x)

// B=8, Cin=768, H=W=64, N=4096, NT=32768, MID=256, INTER=128, OUT=20

__device__ inline void gl_lds16(const _Float16* g, _Float16* l) {
    __builtin_amdgcn_global_load_lds(
        (const __attribute__((address_space(1))) unsigned int*)g,
        (__attribute__((address_space(3))) unsigned int*)l, 16, 0, 0);
}

// ---------------------------------------------------------------------------
// Weight fp32->fp16 conversion. w_theta pre-scaled by log2(e) (exact f32 fold).
// ---------------------------------------------------------------------------
__global__ __launch_bounds__(256) void k_convert(
    const float* __restrict__ w_conv, const float* __restrict__ w_theta,
    const float* __restrict__ w_phi, const float* __restrict__ w_g,
    _Float16* __restrict__ w_conv_h, _Float16* __restrict__ w_theta_h,
    _Float16* __restrict__ w_phi_h, _Float16* __restrict__ w_g_h)
{
    int tid = blockIdx.x * 256 + threadIdx.x;
    int nth = gridDim.x * 256;
    for (int i = tid; i < 256 * 768; i += nth) w_conv_h[i] = (_Float16)w_conv[i];
    for (int i = tid; i < 128 * 256; i += nth) {
        w_theta_h[i] = (_Float16)(w_theta[i] * 1.44269504f);
        w_phi_h[i]   = (_Float16)w_phi[i];
        w_g_h[i]     = (_Float16)w_g[i];
    }
}

// ---------------------------------------------------------------------------
// Fold W->BN->out: Acat[32][384] fp16, c0[32] f32.
// ---------------------------------------------------------------------------
__global__ __launch_bounds__(256) void k_fold(
    const float* __restrict__ w_W, const float* __restrict__ b_W,
    const float* __restrict__ gamma, const float* __restrict__ beta,
    const float* __restrict__ mean, const float* __restrict__ var,
    const float* __restrict__ w_out, const float* __restrict__ b_out,
    _Float16* __restrict__ Acat, float* __restrict__ c0)
{
    int u = blockIdx.x, t = threadIdx.x;
    __shared__ float woi[256];
    __shared__ float wcv[256];
    if (u >= 20) {
        for (int k = t; k < 384; k += 256) Acat[u * 384 + k] = (_Float16)0.f;
        if (t == 0) c0[u] = 0.f;
        return;
    }
    {
        float inv = gamma[t] * rsqrtf(var[t] + 1e-5f);
        float wo = w_out[u * 256 + t];
        woi[t] = wo * inv;
        wcv[t] = wo * (b_W[t] * inv + beta[t] - mean[t] * inv);
    }
    __syncthreads();
    for (int k = t; k < 384; k += 256) {
        float v;
        if (k < 128) {
            v = 0.f;
            for (int o = 0; o < 256; ++o) v += woi[o] * w_W[o * 128 + k];
        } else {
            v = w_out[u * 256 + (k - 128)];
        }
        Acat[u * 384 + k] = (_Float16)v;
    }
    if (t == 0) {
        float s = b_out[u];
        for (int o = 0; o < 256; ++o) s += wcv[o];
        c0[u] = s;
    }
}

// ---------------------------------------------------------------------------
// Fused transpose+convert+conv GEMM.
// X [b][768][4096] f32 (n-contiguous) -> P [(b*4096+n)][256] fp16,
// P[row][o] = sum_c X[b][c][n] * W[o][c].
// grid (2 o-tiles, 256 row-tiles, 2 inputs); block 256; tile 128x128, BK=64.
// A-tile is transposed in registers: each thread loads 8 c-rows x float4 (4 n),
// repacks to 4 half8 (8 c each) -> ds_write_b128 into 72-padded [n][c] tile.
// ---------------------------------------------------------------------------
__global__ __launch_bounds__(256) void k_conv(
    const float* __restrict__ X1, const float* __restrict__ X2,
    const _Float16* __restrict__ W, _Float16* __restrict__ P1,
    _Float16* __restrict__ P2)
{
    int z = blockIdx.z;
    const float* X = (z ? X2 : X1);
    _Float16* P = (z ? P2 : P1);
    int row0 = blockIdx.y * 128;          // global row (b*4096+n)
    int b = row0 >> 12, n0 = row0 & 4095; // 128-row tile stays inside one batch
    int o0 = blockIdx.x * 128;
    const float* Xb = X + (size_t)b * 768 * 4096;

    __shared__ _Float16 As[128][72];      // [n][c]
    __shared__ _Float16 Bs[128][72];      // [o][c]
    int t = threadIdx.x, wave = t >> 6, lane = t & 63;
    int wm = (wave >> 1) * 64, wn = (wave & 1) * 64;
    int fl = lane & 15, fq = lane >> 4;
    int cg = t >> 5;                      // c-group 0..7 (8 c's each)
    int n4 = (t & 31) * 4;                // 4 n's per thread

    floatx4 acc[4][4];
#pragma unroll
    for (int i = 0; i < 4; ++i)
#pragma unroll
        for (int j = 0; j < 4; ++j) acc[i][j] = (floatx4){0.f, 0.f, 0.f, 0.f};

    for (int ko = 0; ko < 768; ko += 64) {
        // load 8 c-rows x 4 n (f32, coalesced along n)
        float4 v[8];
#pragma unroll
        for (int cc = 0; cc < 8; ++cc)
            v[cc] = *(const float4*)(Xb + (size_t)(ko + cg * 8 + cc) * 4096 + n0 + n4);
        // B tile: W[(o0+o)*768 + ko + c]; thread: o=t>>1, 2 half8
        int ow = t >> 1, cs = (t & 1) * 32;
        half8 b0 = *(const half8*)(W + (size_t)(o0 + ow) * 768 + ko + cs);
        half8 b1 = *(const half8*)(W + (size_t)(o0 + ow) * 768 + ko + cs + 8);
        half8 b2 = *(const half8*)(W + (size_t)(o0 + ow) * 768 + ko + cs + 16);
        half8 b3 = *(const half8*)(W + (size_t)(o0 + ow) * 768 + ko + cs + 24);
        __syncthreads();
#pragma unroll
        for (int nn = 0; nn < 4; ++nn) {
            half8 h;
#pragma unroll
            for (int cc = 0; cc < 8; ++cc)
                h[cc] = (_Float16)((const float*)&v[cc])[nn];
            *(half8*)&As[n4 + nn][cg * 8] = h;
        }
        *(half8*)&Bs[ow][cs]      = b0;
        *(half8*)&Bs[ow][cs + 8]  = b1;
        *(half8*)&Bs[ow][cs + 16] = b2;
        *(half8*)&Bs[ow][cs + 24] = b3;
        __syncthreads();
#pragma unroll
        for (int kc = 0; kc < 2; ++kc) {
            half8 af[4], bf[4];
#pragma unroll
            for (int i = 0; i < 4; ++i)
                af[i] = *(const half8*)&As[wm + 16 * i + fl][kc * 32 + 8 * fq];
#pragma unroll
            for (int j = 0; j < 4; ++j)
                bf[j] = *(const half8*)&Bs[wn + 16 * j + fl][kc * 32 + 8 * fq];
#pragma unroll
            for (int i = 0; i < 4; ++i)
#pragma unroll
                for (int j = 0; j < 4; ++j) acc[i][j] = MFMA16(af[i], bf[j], acc[i][j]);
        }
    }
#pragma unroll
    for (int i = 0; i < 4; ++i)
#pragma unroll
        for (int j = 0; j < 4; ++j) {
            int row = row0 + wm + 16 * i + 4 * fq;
            int col = o0 + wn + 16 * j + fl;
#pragma unroll
            for (int r = 0; r < 4; ++r)
                P[(size_t)(row + r) * 256 + col] = (_Float16)acc[i][j][r];
        }
}

// ---------------------------------------------------------------------------
// m97-style NT GEMM with global_load_lds staging. Tile 128x128, BK=64.
// ---------------------------------------------------------------------------
__global__ __launch_bounds__(256) void k_gemm_lds(
    const _Float16* __restrict__ A, const _Float16* __restrict__ B,
    _Float16* __restrict__ C, int K, int ldc)
{
    int m0 = blockIdx.x * 128, n0 = blockIdx.y * 128;
    __shared__ _Float16 As[128 * 64];
    __shared__ _Float16 Bs[128 * 64];
    int t = threadIdx.x, wave = t >> 6, lane = t & 63;
    int wm = (wave >> 1) * 64, wn = (wave & 1) * 64;
    int fl = lane & 15, fq = lane >> 4;
    int lrow = wave * 8 + (lane >> 3);
    int lkoff = (lane & 7) * 8;

    floatx4 acc[4][4];
#pragma unroll
    for (int i = 0; i < 4; ++i)
#pragma unroll
        for (int j = 0; j < 4; ++j) acc[i][j] = (floatx4){0.f, 0.f, 0.f, 0.f};

    for (int ko = 0; ko < K; ko += 64) {
        __syncthreads();
#pragma unroll
        for (int q = 0; q < 4; ++q) {
            int row = q * 32 + lrow;
            gl_lds16(A + (size_t)(m0 + row) * K + ko + lkoff,
                     As + q * 2048 + wave * 512);
            gl_lds16(B + (size_t)(n0 + row) * K + ko + lkoff,
                     Bs + q * 2048 + wave * 512);
        }
        __syncthreads();
#pragma unroll
        for (int kc = 0; kc < 2; ++kc) {
            half8 af[4], bf[4];
#pragma unroll
            for (int i = 0; i < 4; ++i)
                af[i] = *(const half8*)&As[(wm + 16 * i + fl) * 64 + kc * 32 + 8 * fq];
#pragma unroll
            for (int j = 0; j < 4; ++j)
                bf[j] = *(const half8*)&Bs[(wn + 16 * j + fl) * 64 + kc * 32 + 8 * fq];
#pragma unroll
            for (int i = 0; i < 4; ++i)
#pragma unroll
                for (int j = 0; j < 4; ++j) acc[i][j] = MFMA16(af[i], bf[j], acc[i][j]);
        }
    }
#pragma unroll
    for (int i = 0; i < 4; ++i)
#pragma unroll
        for (int j = 0; j < 4; ++j) {
            int row = m0 + wm + 16 * i + 4 * fq;
            int col = n0 + wn + 16 * j + fl;
#pragma unroll
            for (int r = 0; r < 4; ++r)
                C[(size_t)(row + r) * ldc + col] = (_Float16)acc[i][j][r];
        }
}

// ---------------------------------------------------------------------------
// NT GEMM (padded LDS, VGPR staging) for the g projection (perm output).
// perm: col 32B+16h+4q+e -> 32B+8q+4h+e
// ---------------------------------------------------------------------------
__global__ __launch_bounds__(256) void k_gemm_nt(
    const _Float16* __restrict__ A, const _Float16* __restrict__ B,
    _Float16* __restrict__ C, int K, int ldc, int perm)
{
    int m0 = blockIdx.x * 128, n0 = blockIdx.y * 128;
    __shared__ _Float16 As[128][72];
    __shared__ _Float16 Bs[128][72];
    int t = threadIdx.x, wave = t >> 6, lane = t & 63;
    int wm = (wave >> 1) * 64, wn = (wave & 1) * 64;
    int fl = lane & 15, fq = lane >> 4;
    int sr = t >> 2, sc = (t & 3) * 8;

    floatx4 acc[4][4];
#pragma unroll
    for (int i = 0; i < 4; ++i)
#pragma unroll
        for (int j = 0; j < 4; ++j) acc[i][j] = (floatx4){0.f, 0.f, 0.f, 0.f};

    for (int ko = 0; ko < K; ko += 32) {
        __syncthreads();
        half8 av0 = *(const half8*)(A + (size_t)(m0 + sr) * K + ko + sc);
        half8 av1 = *(const half8*)(A + (size_t)(m0 + sr + 64) * K + ko + sc);
        half8 bv0 = *(const half8*)(B + (size_t)(n0 + sr) * K + ko + sc);
        half8 bv1 = *(const half8*)(B + (size_t)(n0 + sr + 64) * K + ko + sc);
        *(half8*)&As[sr][sc] = av0;
        *(half8*)&As[sr + 64][sc] = av1;
        *(half8*)&Bs[sr][sc] = bv0;
        *(half8*)&Bs[sr + 64][sc] = bv1;
        __syncthreads();
        half8 af[4], bf[4];
#pragma unroll
        for (int i = 0; i < 4; ++i) af[i] = *(const half8*)&As[wm + 16 * i + fl][8 * fq];
#pragma unroll
        for (int j = 0; j < 4; ++j) bf[j] = *(const half8*)&Bs[wn + 16 * j + fl][8 * fq];
#pragma unroll
        for (int i = 0; i < 4; ++i)
#pragma unroll
            for (int j = 0; j < 4; ++j) acc[i][j] = MFMA16(af[i], bf[j], acc[i][j]);
    }
#pragma unroll
    for (int i = 0; i < 4; ++i)
#pragma unroll
        for (int j = 0; j < 4; ++j) {
            int row = m0 + wm + 16 * i + 4 * fq;
            int col = n0 + wn + 16 * j + fl;
            int cs2 = perm ? ((col & ~31) | (((col >> 2) & 3) << 3) |
                              (((col >> 4) & 1) << 2) | (col & 3))
                           : col;
#pragma unroll
            for (int r = 0; r < 4; ++r)
                C[(size_t)(row + r) * ldc + cs2] = (_Float16)acc[i][j][r];
        }
}

// ---------------------------------------------------------------------------
// Flash attention, S^T scheme, log2-domain softmax.
// Grid 1024: b = bi&7 (XCD affinity), iblk = (bi>>3)&31, jh = bi>>8 (j-quarter).
// launch_bounds(256,2): compiler keeps ~128 VGPR (NO spill — the (,4) variant
// capped at 64 VGPR and spilled 560 MB to scratch, round-3 regression).
// ---------------------------------------------------------------------------
__global__ __launch_bounds__(256, 2) void k_attn3(
    const _Float16* __restrict__ theta_t, const _Float16* __restrict__ phi_t,
    const _Float16* __restrict__ gbuf, float* __restrict__ Opart,
    float* __restrict__ Mp, float* __restrict__ Lp)
{
    int bi = blockIdx.x;
    int b = bi & 7;
    int r = bi >> 3;
    int iblk = r & 31, jh = r >> 5;
    int i0g = b * 4096 + iblk * 128;
    int t = threadIdx.x, wave = t >> 6, lane = t & 63;
    int fl = lane & 15, fq = lane >> 4;
    int iw = i0g + wave * 32;

    __shared__ _Float16 Ks[64][132];
    __shared__ _Float16 Gs[128][68];

    half8 qf[2][4];
#pragma unroll
    for (int it = 0; it < 2; ++it)
#pragma unroll
        for (int kc = 0; kc < 4; ++kc)
            qf[it][kc] = *(const half8*)(theta_t +
                (size_t)(iw + 16 * it + fl) * 128 + kc * 32 + 8 * fq);

    floatx4 O[8][2];
#pragma unroll
    for (int ct = 0; ct < 8; ++ct)
#pragma unroll
        for (int it = 0; it < 2; ++it) O[ct][it] = (floatx4){0.f, 0.f, 0.f, 0.f};
    float m[2] = {-1e30f, -1e30f}, l[2] = {0.f, 0.f};

    int jbase = b * 4096 + jh * 1024;
    for (int jc = 0; jc < 16; ++jc) {
        int j0g = jbase + jc * 64;
        __syncthreads();
        {
            int jr = t >> 2, cs = (t & 3) * 32;
            const _Float16* src = phi_t + (size_t)(j0g + jr) * 128 + cs;
#pragma unroll
            for (int e = 0; e < 4; ++e)
                *(half8*)&Ks[jr][cs + 8 * e] = *(const half8*)(src + 8 * e);
        }
        {
            int c = t >> 1, js = (t & 1) * 32;
            const _Float16* src = gbuf + (size_t)c * 32768 + j0g + js;
#pragma unroll
            for (int e = 0; e < 4; ++e)
                *(half8*)&Gs[c][js + 8 * e] = *(const half8*)(src + 8 * e);
        }
        __syncthreads();

        floatx4 S[4][2];
#pragma unroll
        for (int jt = 0; jt < 4; ++jt)
#pragma unroll
            for (int it = 0; it < 2; ++it) S[jt][it] = (floatx4){0.f, 0.f, 0.f, 0.f};
#pragma unroll
        for (int kc = 0; kc < 4; ++kc)
#pragma unroll
            for (int jt = 0; jt < 4; ++jt) {
                half8 af = *(const half8*)&Ks[16 * jt + fl][kc * 32 + 8 * fq];
                S[jt][0] = MFMA16(af, qf[0][kc], S[jt][0]);
                S[jt][1] = MFMA16(af, qf[1][kc], S[jt][1]);
            }

        float mx[2];
#pragma unroll
        for (int it = 0; it < 2; ++it) {
            float v = S[0][it][0];
#pragma unroll
            for (int jt = 0; jt < 4; ++jt)
#pragma unroll
                for (int rr = 0; rr < 4; ++rr) v = fmaxf(v, S[jt][it][rr]);
            v = fmaxf(v, __shfl_xor(v, 16, 64));
            v = fmaxf(v, __shfl_xor(v, 32, 64));
            mx[it] = v;
        }
        float mn0 = fmaxf(m[0], mx[0]), mn1 = fmaxf(m[1], mx[1]);
        bool up = (mn0 > m[0]) || (mn1 > m[1]);
        float a0 = EXP2F(m[0] - mn0), a1 = EXP2F(m[1] - mn1);
        m[0] = mn0; m[1] = mn1;

        half8 pk[2][2];
#pragma unroll
        for (int it = 0; it < 2; ++it) {
            float mn = it ? mn1 : mn0;
            float sum = 0.f;
#pragma unroll
            for (int jt = 0; jt < 4; ++jt)
#pragma unroll
                for (int rr = 0; rr < 4; ++rr) {
                    float pv = EXP2F(S[jt][it][rr] - mn);
                    S[jt][it][rr] = pv;
                    sum += pv;
                }
            sum += __shfl_xor(sum, 16, 64);
            sum += __shfl_xor(sum, 32, 64);
            l[it] = l[it] * (it ? a1 : a0) + sum;
#pragma unroll
            for (int kj = 0; kj < 2; ++kj)
#pragma unroll
                for (int e = 0; e < 8; ++e)
                    pk[it][kj][e] = (_Float16)S[2 * kj + (e >> 2)][it][e & 3];
        }
        if (__ballot(up) != 0ull) {
#pragma unroll
            for (int ct = 0; ct < 8; ++ct)
#pragma unroll
                for (int rr = 0; rr < 4; ++rr) {
                    O[ct][0][rr] *= a0;
                    O[ct][1][rr] *= a1;
                }
        }
#pragma unroll
        for (int kj = 0; kj < 2; ++kj)
#pragma unroll
            for (int ct = 0; ct < 8; ++ct) {
                half8 gf = *(const half8*)&Gs[16 * ct + fl][kj * 32 + 8 * fq];
                O[ct][0] = MFMA16(gf, pk[0][kj], O[ct][0]);
                O[ct][1] = MFMA16(gf, pk[1][kj], O[ct][1]);
            }
    }

#pragma unroll
    for (int it = 0; it < 2; ++it) {
        size_t ig = (size_t)jh * 32768 + iw + 16 * it + fl;
#pragma unroll
        for (int ct = 0; ct < 8; ++ct)
            *(floatx4*)&Opart[ig * 128 + 16 * ct + 4 * fq] = O[ct][it];
        if (fq == 0) { Mp[ig] = m[it]; Lp[ig] = l[it]; }
    }
}

// ---------------------------------------------------------------------------
// Merge 4 j-quarter partials -> y_t [(b*4096+i)][128] fp16 (log2 domain)
// ---------------------------------------------------------------------------
__global__ __launch_bounds__(256) void k_merge(
    const float* __restrict__ Opart, const float* __restrict__ Mp,
    const float* __restrict__ Lp, _Float16* __restrict__ y_t)
{
    int g = blockIdx.x * 256 + threadIdx.x;
    int i = g >> 5, cb = (g & 31) * 4;
    float mk[4], lk[4];
    float M = -1e30f;
#pragma unroll
    for (int k = 0; k < 4; ++k) {
        mk[k] = Mp[k * 32768 + i];
        lk[k] = Lp[k * 32768 + i];
        M = fmaxf(M, mk[k]);
    }
    float w[4], den = 0.f;
#pragma unroll
    for (int k = 0; k < 4; ++k) {
        w[k] = EXP2F(mk[k] - M);
        den += w[k] * lk[k];
    }
    float inv = 1.f / den;
    float acc[4] = {0.f, 0.f, 0.f, 0.f};
#pragma unroll
    for (int k = 0; k < 4; ++k) {
        float4 o = *(const float4*)&Opart[((size_t)k * 32768 + i) * 128 + cb];
        float wk = w[k] * inv;
        acc[0] += wk * o.x; acc[1] += wk * o.y;
        acc[2] += wk * o.z; acc[3] += wk * o.w;
    }
    half4v y;
#pragma unroll
    for (int e = 0; e < 4; ++e) y[e] = (_Float16)acc[e];
    *(half4v*)&y_t[(size_t)i * 128 + cb] = y;
}

// ---------------------------------------------------------------------------
// Epilogue GEMM: out[u][ng] = sum_k Acat[u][k]*concat(y_t,x1p)[ng][k] + c0[u]
// ---------------------------------------------------------------------------
__global__ __launch_bounds__(256) void k_out(
    const _Float16* __restrict__ y_t, const _Float16* __restrict__ x1p_t,
    const _Float16* __restrict__ Acat, const float* __restrict__ c0,
    float* __restrict__ out)
{
    int n0 = blockIdx.x * 128;
    __shared__ _Float16 As[32][72];
    __shared__ _Float16 Bs[128][72];
    __shared__ float c0s[32];
    int t = threadIdx.x, wave = t >> 6, lane = t & 63;
    int fl = lane & 15, fq = lane >> 4;
    int wn = wave * 32;
    if (t < 32) c0s[t] = c0[t];

    floatx4 acc[2][2];
#pragma unroll
    for (int i = 0; i < 2; ++i)
#pragma unroll
        for (int j = 0; j < 2; ++j) acc[i][j] = (floatx4){0.f, 0.f, 0.f, 0.f};

    for (int ko = 0; ko < 12; ++ko) {
        int kg = ko * 32;
        __syncthreads();
        {
            int n = t >> 1, ks = (t & 1) * 16;
            const _Float16* src = (kg < 128)
                ? y_t + (size_t)(n0 + n) * 128 + kg + ks
                : x1p_t + (size_t)(n0 + n) * 256 + (kg - 128) + ks;
            *(half8*)&Bs[n][ks]     = *(const half8*)src;
            *(half8*)&Bs[n][ks + 8] = *(const half8*)(src + 8);
        }
        if (t < 128) {
            int mm = t >> 2, ks = (t & 3) * 8;
            *(half8*)&As[mm][ks] = *(const half8*)(Acat + mm * 384 + kg + ks);
        }
        __syncthreads();
        half8 af[2], bf[2];
#pragma unroll
        for (int mt = 0; mt < 2; ++mt) af[mt] = *(const half8*)&As[16 * mt + fl][8 * fq];
#pragma unroll
        for (int nt = 0; nt < 2; ++nt) bf[nt] = *(const half8*)&Bs[wn + 16 * nt + fl][8 * fq];
#pragma unroll
        for (int mt = 0; mt < 2; ++mt)
#pragma unroll
            for (int nt = 0; nt < 2; ++nt) acc[mt][nt] = MFMA16(af[mt], bf[nt], acc[mt][nt]);
    }
#pragma unroll
    for (int mt = 0; mt < 2; ++mt)
#pragma unroll
        for (int nt = 0; nt < 2; ++nt)
#pragma unroll
            for (int r = 0; r < 4; ++r) {
                int u = 16 * mt + 4 * fq + r;
                if (u < 20) {
                    int ng = n0 + wn + 16 * nt + fl;
                    int b = ng >> 12, n = ng & 4095;
                    out[((size_t)b * 20 + u) * 4096 + n] = acc[mt][nt][r] + c0s[u];
                }
            }
}

// ---------------------------------------------------------------------------
extern "C" void kernel_launch(void* const* d_in, const int* in_sizes, int n_in,
                              void* d_out, int out_size, void* d_ws, size_t ws_size,
                              hipStream_t stream)
{
    const float* x1     = (const float*)d_in[0];
    const float* x2     = (const float*)d_in[1];
    const float* w_conv = (const float*)d_in[2];
    const float* w_theta= (const float*)d_in[3];
    const float* w_phi  = (const float*)d_in[4];
    const float* w_g    = (const float*)d_in[5];
    const float* w_W    = (const float*)d_in[6];
    const float* b_W    = (const float*)d_in[7];
    const float* gamma  = (const float*)d_in[8];
    const float* beta   = (const float*)d_in[9];
    const float* mean   = (const float*)d_in[10];
    const float* var    = (const float*)d_in[11];
    const float* w_out  = (const float*)d_in[12];
    const float* b_out  = (const float*)d_in[13];
    float* out = (float*)d_out;
    char* ws = (char*)d_ws;

    // workspace layout (bytes)
    _Float16* x1p      = (_Float16*)(ws + 100663296);  // [32768][256] (alive to end)
    _Float16* x2p      = (_Float16*)(ws + 117440512);  // [32768][256] (dead after g/phi)
    _Float16* theta_t  = (_Float16*)(ws + 0);          // [32768][128]
    _Float16* phi_t    = (_Float16*)(ws + 8388608);    // [32768][128]
    _Float16* gbuf     = (_Float16*)(ws + 16777216);   // [128][32768] permuted
    _Float16* y_t      = (_Float16*)(ws + 25165824);   // [32768][128]
    float*    Opart    = (float*)   (ws + 33554432);   // [4][32768][128] f32 (ends 100663296)
    float*    Mp       = (float*)   (ws + 117440512);  // [4][32768] (over dead x2p)
    float*    Lp       = (float*)   (ws + 117964800);  // [4][32768]
    _Float16* w_conv_h = (_Float16*)(ws + 134217728);  // [256][768]
    _Float16* w_theta_h= (_Float16*)(ws + 134610944);  // [128][256] (log2e-scaled)
    _Float16* w_phi_h  = (_Float16*)(ws + 134676480);  // [128][256]
    _Float16* w_g_h    = (_Float16*)(ws + 134742016);  // [128][256]
    _Float16* Acat     = (_Float16*)(ws + 134807552);  // [32][384]
    float*    c0       = (float*)   (ws + 134832128);  // [32]

    k_convert<<<64, 256, 0, stream>>>(w_conv, w_theta, w_phi, w_g,
                                      w_conv_h, w_theta_h, w_phi_h, w_g_h);
    k_fold<<<32, 256, 0, stream>>>(w_W, b_W, gamma, beta, mean, var,
                                   w_out, b_out, Acat, c0);
    k_conv<<<dim3(2, 256, 2), 256, 0, stream>>>(x1, x2, w_conv_h, x1p, x2p);
    k_gemm_lds<<<dim3(256, 1), 256, 0, stream>>>(x1p, w_theta_h, theta_t, 256, 128);
    k_gemm_lds<<<dim3(256, 1), 256, 0, stream>>>(x2p, w_phi_h, phi_t, 256, 128);
    k_gemm_nt<<<dim3(1, 256), 256, 0, stream>>>(w_g_h, x2p, gbuf, 256, 32768, 1);
    k_attn3<<<1024, 256, 0, stream>>>(theta_t, phi_t, gbuf, Opart, Mp, Lp);
    k_merge<<<4096, 256, 0, stream>>>(Opart, Mp, Lp, y_t);
    k_out<<<256, 256, 0, stream>>>(y_t, x1p, Acat, c0, out);
    (void)in_sizes; (void)n_in; (void)out_size; (void)ws_size;
}